// Round 12
// baseline (391.278 us; speedup 1.0000x reference)
//
#include <hip/hip_runtime.h>
#include <hip/hip_bf16.h>

// Problem constants (reference: B,K,N,F,H = 20000,10,100000,256,128)
constexpr int B_ = 20000;
constexpr int K_ = 10;
constexpr int N_ = 100000;
constexpr int F_ = 256;
constexpr int H_ = 128;
constexpr int RW = 3 * H_;  // interleaved qkv row width (384 ushorts = 768 B)

typedef __attribute__((ext_vector_type(8))) short bf16x8;
typedef __attribute__((ext_vector_type(4))) float f32x4;

__device__ __forceinline__ unsigned short f2bf(float x) {
  unsigned int u = __builtin_bit_cast(unsigned int, x);
  unsigned int r = u + 0x7fffu + ((u >> 16) & 1u);
  return (unsigned short)(r >> 16);
}

__device__ __forceinline__ float bf2f(unsigned int u16) {
  return __builtin_bit_cast(float, u16 << 16);
}

// RNE pack of two f32 -> 2xbf16 in one dword (lo -> [15:0], hi -> [31:16]).
__device__ __forceinline__ unsigned int cvt_pk_bf16(float lo, float hi) {
  unsigned int r;
  asm("v_cvt_pk_bf16_f32 %0, %1, %2" : "=v"(r) : "v"(lo), "v"(hi));
  return r;
}

__device__ __forceinline__ float fast_tanh(float x) {
  float e = __expf(2.0f * x);
  return 1.0f - 2.0f * __builtin_amdgcn_rcpf(e + 1.0f);
}

// ---------------------------------------------------------------------------
// Prep: weights -> fragment-major bf16 layout (proven correct; unchanged).
// wat2 chunks (p, ks∈8, c∈8), 512 bf16 each: elem(lane,j) = Wa_p[32ks+8(lane>>4)+j][16c+(lane&15)]
// wbt2 chunks (p, c2∈8, ks2∈4):              elem(lane,j) = Wb_p[32ks2+8(lane>>4)+j][16c2+(lane&15)]
// ---------------------------------------------------------------------------
__global__ __launch_bounds__(256) void prep_kernel(
    const float* __restrict__ W1a, const float* __restrict__ W1b,
    const float* __restrict__ W2a, const float* __restrict__ W2b,
    const float* __restrict__ W3a, const float* __restrict__ W3b,
    unsigned short* __restrict__ wat2, unsigned short* __restrict__ wbt2) {
  const float* Wa[3] = {W1a, W2a, W3a};
  const float* Wb[3] = {W1b, W2b, W3b};
  int g = blockIdx.x * 256 + threadIdx.x;
  if (g < 3 * 64 * 512) {
    int chunk = g >> 9;
    int e = g & 511;
    int lane = e >> 3, j = e & 7;
    int c = chunk & 7;
    int ks = (chunk >> 3) & 7;
    int p = chunk >> 6;
    int k = 32 * ks + 8 * (lane >> 4) + j;
    int h = 16 * c + (lane & 15);
    wat2[g] = f2bf(Wa[p][k * H_ + h]);
  } else {
    int g2 = g - 3 * 64 * 512;
    int chunk = g2 >> 9;
    int e = g2 & 511;
    int lane = e >> 3, j = e & 7;
    int ks2 = chunk & 3;
    int c2 = (chunk >> 2) & 7;
    int p = chunk >> 5;
    int k = 32 * ks2 + 8 * (lane >> 4) + j;
    int h2 = 16 * c2 + (lane & 15);
    wbt2[g2] = f2bf(Wb[p][k * H_ + h2]);
  }
}

// ---------------------------------------------------------------------------
// Projections — R12: the R9xR4 synthesis. Evidence: R9 (per-wave
// independent, 0 barriers) failed ONLY on occupancy (1.4 waves/SIMD);
// R4/R1 (lockstep) failed ONLY on barrier phase-latency serialization;
// R11 falsified the LDS-pipe theory (conflicts halved, time +70%).
// Structure: 256 thr / 4 waves, MT=64. Cooperative coalesced stage of xs
// (ONE barrier, the only one). Then each wave owns node-tile w (16 nodes)
// END-TO-END, fully independent:
//   * layer-1: acc[8] (all 8 h-tiles); per ks ONE ds_read feeds 8 MFMAs
//     (8 independent chains, minimal LDS traffic);
//   * C->A transpose via per-wave scratch [16][68] dwords (R8/R9-verified
//     mapping: write uint2 at 8hp+2q, read b128 at 16ks2+4q) — same wave,
//     lgkmcnt orders it, NO barrier;
//   * layer-2: ac2[8]; per ks2 ONE ds_read feeds 8 MFMAs; store.
// LDS = 33792 (xs) + 4x4352 (scratch) = 51200 -> 3 blocks/CU = 12
// free-running waves/CU. Weight chunks re-read per wave (L2-resident,
// overlappable without barriers) — the accepted price of independence.
// ---------------------------------------------------------------------------
constexpr int MT = 64;
constexpr int XS = F_ + 8;  // 264 shorts = 528 B row stride (proven)
constexpr int SPAD = 68;    // dwords per scratch row (64 + 4 pad, R9-proven)

__global__ __launch_bounds__(256) void proj_kernel(
    const float* __restrict__ E,
    const unsigned short* __restrict__ wat2,
    const unsigned short* __restrict__ wbt2,
    unsigned short* __restrict__ qkvI) {
  __shared__ unsigned short xs[MT * XS];        // 33792 B
  __shared__ unsigned int scr[4 * 16 * SPAD];   // 17408 B

  const int tid = threadIdx.x;
  const int lane = tid & 63;
  const int w = tid >> 6;    // 0..3 : owns node-tile w (nodes 16w..16w+15)
  const int l15 = lane & 15;
  const int q = lane >> 4;
  const int row0 = blockIdx.x * MT;
  unsigned int* scw = scr + w * (16 * SPAD);

  // ---- stage X tile (fp32 -> bf16), coalesced; clamp OOB rows
  {
    const float4* Eg = (const float4*)E;
#pragma unroll
    for (int it = 0; it < 16; ++it) {
      int i = tid + 256 * it;
      int r = i >> 6;
      int c4 = i & 63;
      int row = row0 + r;
      if (row >= N_) row = N_ - 1;
      float4 v = Eg[(size_t)row * (F_ / 4) + c4];
      unsigned int lo = cvt_pk_bf16(v.x, v.y);
      unsigned int hi = cvt_pk_bf16(v.z, v.w);
      *(uint2*)&xs[r * XS + c4 * 4] = make_uint2(lo, hi);
    }
  }
  __syncthreads();  // the ONLY barrier in this kernel

  for (int p = 0; p < 3; ++p) {
    const unsigned short* __restrict__ wa = wat2 + p * (64 * 512);
    const unsigned short* __restrict__ wb = wbt2 + p * (32 * 512);

    // ---- layer 1, K=256: acc[hp] (h-tile hp, node-tile w).
    f32x4 acc[8];
#pragma unroll
    for (int hp = 0; hp < 8; ++hp) acc[hp] = (f32x4)0.0f;

#pragma unroll
    for (int ks = 0; ks < 8; ++ks) {
      bf16x8 bx = *(const bf16x8*)&xs[(16 * w + l15) * XS + 32 * ks + 8 * q];
#pragma unroll
      for (int hp = 0; hp < 8; ++hp) {
        bf16x8 af = *(const bf16x8*)&wa[(ks * 8 + hp) * 512 + lane * 8];
        acc[hp] = __builtin_amdgcn_mfma_f32_16x16x32_bf16(af, bx, acc[hp], 0, 0, 0);
      }
    }

    // ---- tanh + pack -> per-wave scratch (intra-wave: NO barrier).
    // value (h = 16hp+4q+r, node col l15) -> dword idx h/2 = 8hp+2q+e
#pragma unroll
    for (int hp = 0; hp < 8; ++hp) {
      unsigned int lo = cvt_pk_bf16(fast_tanh(acc[hp][0]), fast_tanh(acc[hp][1]));
      unsigned int hi = cvt_pk_bf16(fast_tanh(acc[hp][2]), fast_tanh(acc[hp][3]));
      *(uint2*)&scw[l15 * SPAD + 8 * hp + 2 * q] = make_uint2(lo, hi);
    }

    // ---- layer 2, K=128: ac2[c2]; bt read back from scratch (b128).
    f32x4 ac2[8];
#pragma unroll
    for (int c2 = 0; c2 < 8; ++c2) ac2[c2] = (f32x4)0.0f;

#pragma unroll
    for (int ks2 = 0; ks2 < 4; ++ks2) {
      // lane (l15,q) holds T[node l15][32ks2+8q+j] = dwords 16ks2+4q..+3
      bf16x8 bt = *(const bf16x8*)&scw[l15 * SPAD + 16 * ks2 + 4 * q];
#pragma unroll
      for (int c2 = 0; c2 < 8; ++c2) {
        bf16x8 ab = *(const bf16x8*)&wb[(c2 * 4 + ks2) * 512 + lane * 8];
        ac2[c2] = __builtin_amdgcn_mfma_f32_16x16x32_bf16(ab, bt, ac2[c2], 0, 0, 0);
      }
    }

    // ---- store qkv^T: (h2 = 16c2+4q+r, node = 16w+l15) -> 8B stores
#pragma unroll
    for (int c2 = 0; c2 < 8; ++c2) {
      int n = row0 + 16 * w + l15;
      if (n < N_) {
        unsigned int lo = cvt_pk_bf16(ac2[c2][0], ac2[c2][1]);
        unsigned int hi = cvt_pk_bf16(ac2[c2][2], ac2[c2][3]);
        *(uint2*)&qkvI[(size_t)n * RW + p * H_ + 16 * c2 + 4 * q] =
            make_uint2(lo, hi);
      }
    }
  }
}

// ---------------------------------------------------------------------------
// Phase 2: one WAVE per batch node, gathering from interleaved qkvI
// (768 B contiguous per neighbor). No LDS, no barriers. (Unchanged.)
// ---------------------------------------------------------------------------
__global__ __launch_bounds__(256) void agg_kernel(
    const int* __restrict__ nbr,
    const unsigned short* __restrict__ qkvI,
    float* __restrict__ out) {
  const int lane = threadIdx.x & 63;
  const int wv = threadIdx.x >> 6;
  const int b = blockIdx.x * 4 + wv;
  const int l15 = lane & 15;
  const int kg = lane >> 4;

  const int ni = nbr[b * K_ + (l15 < K_ ? l15 : 0)];
  const size_t nbase = (size_t)ni * RW;

  // scores[i][j] = q_i . k_j
  f32x4 sc = (f32x4)0.0f;
#pragma unroll
  for (int k = 0; k < 4; ++k) {
    const int off = k * 32 + kg * 8;
    bf16x8 qf = *(const bf16x8*)&qkvI[nbase + off];
    bf16x8 kf = *(const bf16x8*)&qkvI[nbase + H_ + off];
    sc = __builtin_amdgcn_mfma_f32_16x16x32_bf16(qf, kf, sc, 0, 0, 0);
  }

  if (l15 >= K_) {
#pragma unroll
    for (int r = 0; r < 4; ++r) sc[r] = -3.0e38f;
  }

  float mx[4], e[4], sm[4];
#pragma unroll
  for (int r = 0; r < 4; ++r) mx[r] = sc[r];
#pragma unroll
  for (int st = 1; st < 16; st <<= 1)
#pragma unroll
    for (int r = 0; r < 4; ++r) mx[r] = fmaxf(mx[r], __shfl_xor(mx[r], st, 16));
#pragma unroll
  for (int r = 0; r < 4; ++r) { e[r] = __expf(sc[r] - mx[r]); sm[r] = e[r]; }
#pragma unroll
  for (int st = 1; st < 16; st <<= 1)
#pragma unroll
    for (int r = 0; r < 4; ++r) sm[r] += __shfl_xor(sm[r], st, 16);

  float cs = 0.0f;
#pragma unroll
  for (int r = 0; r < 4; ++r) {
    float a = e[r] * __builtin_amdgcn_rcpf(sm[r]);
    if (kg * 4 + r >= K_) a = 0.0f;
    cs += a;
  }
  cs += __shfl_xor(cs, 16, 64);
  cs += __shfl_xor(cs, 32, 64);

  float o0 = 0.0f, o1 = 0.0f;
#pragma unroll
  for (int j = 0; j < K_; ++j) {
    const float cj = __shfl(cs, j, 64);
    const int nj = __shfl(ni, j, 64);
    const unsigned int v2 =
        *(const unsigned int*)&qkvI[(size_t)nj * RW + 2 * H_ + 2 * lane];
    o0 = fmaf(cj, bf2f(v2 & 0xffffu), o0);
    o1 = fmaf(cj, bf2f(v2 >> 16), o1);
  }
  *(float2*)&out[(size_t)b * H_ + 2 * lane] = make_float2(o0, o1);
}

extern "C" void kernel_launch(void* const* d_in, const int* in_sizes, int n_in,
                              void* d_out, int out_size, void* d_ws, size_t ws_size,
                              hipStream_t stream) {
  const int* nbr = (const int*)d_in[0];
  const float* E = (const float*)d_in[1];
  const float* W1a = (const float*)d_in[2];
  const float* W1b = (const float*)d_in[3];
  const float* W2a = (const float*)d_in[4];
  const float* W2b = (const float*)d_in[5];
  const float* W3a = (const float*)d_in[6];
  const float* W3b = (const float*)d_in[7];
  float* out = (float*)d_out;

  // workspace: qkvI [N][384] bf16 interleaved = 76.8 MB, then frag-major weights
  unsigned short* qkvI = (unsigned short*)d_ws;
  unsigned short* wat2 = qkvI + (size_t)N_ * RW;
  unsigned short* wbt2 = wat2 + (size_t)3 * 64 * 512;

  prep_kernel<<<(3 * 64 * 512 + 3 * 32 * 512) / 256, 256, 0, stream>>>(
      W1a, W1b, W2a, W2b, W3a, W3b, wat2, wbt2);
  proj_kernel<<<(N_ + MT - 1) / MT, 256, 0, stream>>>(E, wat2, wbt2, qkvI);
  agg_kernel<<<B_ / 4, 256, 0, stream>>>(nbr, qkvI, out);
}

// Round 13
// 232.561 us; speedup vs baseline: 1.6825x; 1.6825x over previous
//
#include <hip/hip_runtime.h>
#include <hip/hip_bf16.h>

// Problem constants (reference: B,K,N,F,H = 20000,10,100000,256,128)
constexpr int B_ = 20000;
constexpr int K_ = 10;
constexpr int N_ = 100000;
constexpr int F_ = 256;
constexpr int H_ = 128;
constexpr int RW = 3 * H_;  // interleaved qkv row width (384 ushorts = 768 B)

typedef __attribute__((ext_vector_type(8))) short bf16x8;
typedef __attribute__((ext_vector_type(4))) float f32x4;

__device__ __forceinline__ unsigned short f2bf(float x) {
  unsigned int u = __builtin_bit_cast(unsigned int, x);
  unsigned int r = u + 0x7fffu + ((u >> 16) & 1u);
  return (unsigned short)(r >> 16);
}

__device__ __forceinline__ float bf2f(unsigned int u16) {
  return __builtin_bit_cast(float, u16 << 16);
}

// RNE pack of two f32 -> 2xbf16 in one dword (lo -> [15:0], hi -> [31:16]).
__device__ __forceinline__ unsigned int cvt_pk_bf16(float lo, float hi) {
  unsigned int r;
  asm("v_cvt_pk_bf16_f32 %0, %1, %2" : "=v"(r) : "v"(lo), "v"(hi));
  return r;
}

__device__ __forceinline__ float fast_tanh(float x) {
  float e = __expf(2.0f * x);
  return 1.0f - 2.0f * __builtin_amdgcn_rcpf(e + 1.0f);
}

// ---------------------------------------------------------------------------
// Prep: weights -> fragment-major bf16 layout (proven correct; unchanged).
// wat2 chunks (p, ks∈8, c∈8), 512 bf16 each: elem(lane,j) = Wa_p[32ks+8(lane>>4)+j][16c+(lane&15)]
// wbt2 chunks (p, c2∈8, ks2∈4):              elem(lane,j) = Wb_p[32ks2+8(lane>>4)+j][16c2+(lane&15)]
// ---------------------------------------------------------------------------
__global__ __launch_bounds__(256) void prep_kernel(
    const float* __restrict__ W1a, const float* __restrict__ W1b,
    const float* __restrict__ W2a, const float* __restrict__ W2b,
    const float* __restrict__ W3a, const float* __restrict__ W3b,
    unsigned short* __restrict__ wat2, unsigned short* __restrict__ wbt2) {
  const float* Wa[3] = {W1a, W2a, W3a};
  const float* Wb[3] = {W1b, W2b, W3b};
  int g = blockIdx.x * 256 + threadIdx.x;
  if (g < 3 * 64 * 512) {
    int chunk = g >> 9;
    int e = g & 511;
    int lane = e >> 3, j = e & 7;
    int c = chunk & 7;
    int ks = (chunk >> 3) & 7;
    int p = chunk >> 6;
    int k = 32 * ks + 8 * (lane >> 4) + j;
    int h = 16 * c + (lane & 15);
    wat2[g] = f2bf(Wa[p][k * H_ + h]);
  } else {
    int g2 = g - 3 * 64 * 512;
    int chunk = g2 >> 9;
    int e = g2 & 511;
    int lane = e >> 3, j = e & 7;
    int ks2 = chunk & 3;
    int c2 = (chunk >> 2) & 7;
    int p = chunk >> 5;
    int k = 32 * ks2 + 8 * (lane >> 4) + j;
    int h2 = 16 * c2 + (lane & 15);
    wbt2[g2] = f2bf(Wb[p][k * H_ + h2]);
  }
}

// ---------------------------------------------------------------------------
// Projections — R13: R1 restored (session-best: proj 89.1us, total 236.0)
// + software-pipelined p-loop. Post-R12 closure: per-wave weight-load
// count is THE latency variable (R1=36/wave best; R8-R12 = 72-288/wave,
// monotonically worse). R1's geometry is kept verbatim (512 thr / 8
// waves, MT=64, wave w owns h-tile w, acc[4], all R1 index formulas).
// Schedule change only:
//   * pack(0) needs no preceding barrier (ts never yet read);
//   * l1(p+1) [reads xs only] overlaps the l2(p) phase [reads ts only]
//     -> next projection's weight loads + ds_reads hide under current
//     l2 MFMAs; barriers 7 -> 6; one fewer exposed phase-latency per p.
// ---------------------------------------------------------------------------
constexpr int MT = 64;
constexpr int XS = F_ + 8;  // 264 shorts = 528 B row stride (2-way max, free)
constexpr int TS = H_ + 8;  // 136 shorts = 272 B row stride

__global__ __launch_bounds__(512) void proj_kernel(
    const float* __restrict__ E,
    const unsigned short* __restrict__ wat2,
    const unsigned short* __restrict__ wbt2,
    unsigned short* __restrict__ qkvI) {
  __shared__ unsigned short xs[MT * XS];  // 33792 B
  __shared__ unsigned short ts[MT * TS];  // 17408 B

  const int tid = threadIdx.x;
  const int lane = tid & 63;
  const int w = tid >> 6;    // 0..7 : h-tile owner
  const int l15 = lane & 15;
  const int q = lane >> 4;
  const int row0 = blockIdx.x * MT;

  // ---- stage X tile (fp32 -> bf16), coalesced; clamp OOB rows (insurance)
  {
    const float4* Eg = (const float4*)E;
#pragma unroll
    for (int it = 0; it < 8; ++it) {
      int i = tid + 512 * it;
      int r = i >> 6;
      int c4 = i & 63;
      int row = row0 + r;
      if (row >= N_) row = N_ - 1;
      float4 v = Eg[(size_t)row * (F_ / 4) + c4];
      unsigned int lo = cvt_pk_bf16(v.x, v.y);
      unsigned int hi = cvt_pk_bf16(v.z, v.w);
      *(uint2*)&xs[r * XS + c4 * 4] = make_uint2(lo, hi);
    }
  }
  __syncthreads();  // (1) xs visible

  f32x4 acc[4];

  // ---- layer 1 for p=0 (R1 formulas verbatim)
  {
    const unsigned short* __restrict__ wa = wat2;
#pragma unroll
    for (int nt = 0; nt < 4; ++nt) acc[nt] = (f32x4)0.0f;
#pragma unroll
    for (int ks = 0; ks < 8; ++ks) {
      bf16x8 af = *(const bf16x8*)&wa[(ks * 8 + w) * 512 + lane * 8];
#pragma unroll
      for (int nt = 0; nt < 4; ++nt) {
        bf16x8 bx = *(const bf16x8*)&xs[(16 * nt + l15) * XS + 32 * ks + 8 * q];
        acc[nt] = __builtin_amdgcn_mfma_f32_16x16x32_bf16(af, bx, acc[nt], 0, 0, 0);
      }
    }
  }

  // ---- pack(0): ts never read yet -> NO barrier needed before this.
#pragma unroll
  for (int nt = 0; nt < 4; ++nt) {
    unsigned int lo = cvt_pk_bf16(fast_tanh(acc[nt][0]), fast_tanh(acc[nt][1]));
    unsigned int hi = cvt_pk_bf16(fast_tanh(acc[nt][2]), fast_tanh(acc[nt][3]));
    // value (h = 16*w+4q+r, node = 16nt+l15)
    *(uint2*)&ts[(16 * nt + l15) * TS + 16 * w + 4 * q] = make_uint2(lo, hi);
  }
  __syncthreads();  // (2) pack(0) visible

  for (int p = 0; p < 3; ++p) {
    const unsigned short* __restrict__ wb = wbt2 + p * (32 * 512);

    // ---- layer 2 for p (reads ts), K=128
    f32x4 ac2[4];
#pragma unroll
    for (int nt = 0; nt < 4; ++nt) ac2[nt] = (f32x4)0.0f;
#pragma unroll
    for (int ks2 = 0; ks2 < 4; ++ks2) {
      bf16x8 ab = *(const bf16x8*)&wb[(w * 4 + ks2) * 512 + lane * 8];
#pragma unroll
      for (int nt = 0; nt < 4; ++nt) {
        bf16x8 bt = *(const bf16x8*)&ts[(16 * nt + l15) * TS + 32 * ks2 + 8 * q];
        ac2[nt] = __builtin_amdgcn_mfma_f32_16x16x32_bf16(ab, bt, ac2[nt], 0, 0, 0);
      }
    }

    // ---- store qkv^T for p
#pragma unroll
    for (int nt = 0; nt < 4; ++nt) {
      int n = row0 + 16 * nt + l15;
      if (n < N_) {
        unsigned int lo = cvt_pk_bf16(ac2[nt][0], ac2[nt][1]);
        unsigned int hi = cvt_pk_bf16(ac2[nt][2], ac2[nt][3]);
        *(uint2*)&qkvI[(size_t)n * RW + p * H_ + 16 * w + 4 * q] =
            make_uint2(lo, hi);
      }
    }

    // ---- OVERLAPPED: layer 1 for p+1 (reads xs only — no conflict with
    //      this phase's ts reads above; hides next p's weight-load latency)
    if (p < 2) {
      const unsigned short* __restrict__ wa = wat2 + (p + 1) * (64 * 512);
#pragma unroll
      for (int nt = 0; nt < 4; ++nt) acc[nt] = (f32x4)0.0f;
#pragma unroll
      for (int ks = 0; ks < 8; ++ks) {
        bf16x8 af = *(const bf16x8*)&wa[(ks * 8 + w) * 512 + lane * 8];
#pragma unroll
        for (int nt = 0; nt < 4; ++nt) {
          bf16x8 bx = *(const bf16x8*)&xs[(16 * nt + l15) * XS + 32 * ks + 8 * q];
          acc[nt] = __builtin_amdgcn_mfma_f32_16x16x32_bf16(af, bx, acc[nt], 0, 0, 0);
        }
      }

      __syncthreads();  // (3/5) all ts reads of l2(p) retired

      // ---- pack(p+1) -> ts
#pragma unroll
      for (int nt = 0; nt < 4; ++nt) {
        unsigned int lo = cvt_pk_bf16(fast_tanh(acc[nt][0]), fast_tanh(acc[nt][1]));
        unsigned int hi = cvt_pk_bf16(fast_tanh(acc[nt][2]), fast_tanh(acc[nt][3]));
        *(uint2*)&ts[(16 * nt + l15) * TS + 16 * w + 4 * q] = make_uint2(lo, hi);
      }
      __syncthreads();  // (4/6) pack(p+1) visible
    }
  }
}

// ---------------------------------------------------------------------------
// Phase 2: one WAVE per batch node, gathering from interleaved qkvI
// (768 B contiguous per neighbor). No LDS, no barriers. (Unchanged.)
// ---------------------------------------------------------------------------
__global__ __launch_bounds__(256) void agg_kernel(
    const int* __restrict__ nbr,
    const unsigned short* __restrict__ qkvI,
    float* __restrict__ out) {
  const int lane = threadIdx.x & 63;
  const int wv = threadIdx.x >> 6;
  const int b = blockIdx.x * 4 + wv;
  const int l15 = lane & 15;
  const int kg = lane >> 4;

  const int ni = nbr[b * K_ + (l15 < K_ ? l15 : 0)];
  const size_t nbase = (size_t)ni * RW;

  // scores[i][j] = q_i . k_j
  f32x4 sc = (f32x4)0.0f;
#pragma unroll
  for (int k = 0; k < 4; ++k) {
    const int off = k * 32 + kg * 8;
    bf16x8 qf = *(const bf16x8*)&qkvI[nbase + off];
    bf16x8 kf = *(const bf16x8*)&qkvI[nbase + H_ + off];
    sc = __builtin_amdgcn_mfma_f32_16x16x32_bf16(qf, kf, sc, 0, 0, 0);
  }

  if (l15 >= K_) {
#pragma unroll
    for (int r = 0; r < 4; ++r) sc[r] = -3.0e38f;
  }

  float mx[4], e[4], sm[4];
#pragma unroll
  for (int r = 0; r < 4; ++r) mx[r] = sc[r];
#pragma unroll
  for (int st = 1; st < 16; st <<= 1)
#pragma unroll
    for (int r = 0; r < 4; ++r) mx[r] = fmaxf(mx[r], __shfl_xor(mx[r], st, 16));
#pragma unroll
  for (int r = 0; r < 4; ++r) { e[r] = __expf(sc[r] - mx[r]); sm[r] = e[r]; }
#pragma unroll
  for (int st = 1; st < 16; st <<= 1)
#pragma unroll
    for (int r = 0; r < 4; ++r) sm[r] += __shfl_xor(sm[r], st, 16);

  float cs = 0.0f;
#pragma unroll
  for (int r = 0; r < 4; ++r) {
    float a = e[r] * __builtin_amdgcn_rcpf(sm[r]);
    if (kg * 4 + r >= K_) a = 0.0f;
    cs += a;
  }
  cs += __shfl_xor(cs, 16, 64);
  cs += __shfl_xor(cs, 32, 64);

  float o0 = 0.0f, o1 = 0.0f;
#pragma unroll
  for (int j = 0; j < K_; ++j) {
    const float cj = __shfl(cs, j, 64);
    const int nj = __shfl(ni, j, 64);
    const unsigned int v2 =
        *(const unsigned int*)&qkvI[(size_t)nj * RW + 2 * H_ + 2 * lane];
    o0 = fmaf(cj, bf2f(v2 & 0xffffu), o0);
    o1 = fmaf(cj, bf2f(v2 >> 16), o1);
  }
  *(float2*)&out[(size_t)b * H_ + 2 * lane] = make_float2(o0, o1);
}

extern "C" void kernel_launch(void* const* d_in, const int* in_sizes, int n_in,
                              void* d_out, int out_size, void* d_ws, size_t ws_size,
                              hipStream_t stream) {
  const int* nbr = (const int*)d_in[0];
  const float* E = (const float*)d_in[1];
  const float* W1a = (const float*)d_in[2];
  const float* W1b = (const float*)d_in[3];
  const float* W2a = (const float*)d_in[4];
  const float* W2b = (const float*)d_in[5];
  const float* W3a = (const float*)d_in[6];
  const float* W3b = (const float*)d_in[7];
  float* out = (float*)d_out;

  // workspace: qkvI [N][384] bf16 interleaved = 76.8 MB, then frag-major weights
  unsigned short* qkvI = (unsigned short*)d_ws;
  unsigned short* wat2 = qkvI + (size_t)N_ * RW;
  unsigned short* wbt2 = wat2 + (size_t)3 * 64 * 512;

  prep_kernel<<<(3 * 64 * 512 + 3 * 32 * 512) / 256, 256, 0, stream>>>(
      W1a, W1b, W2a, W2b, W3a, W3b, wat2, wbt2);
  proj_kernel<<<(N_ + MT - 1) / MT, 512, 0, stream>>>(E, wat2, wbt2, qkvI);
  agg_kernel<<<B_ / 4, 256, 0, stream>>>(nbr, qkvI, out);
}